// Round 3
// baseline (631.239 us; speedup 1.0000x reference)
//
#include <hip/hip_runtime.h>

#define NN 8192
#define DD 512
#define EE 262144

typedef __attribute__((ext_vector_type(4))) float f32x4;
typedef __attribute__((ext_vector_type(8))) short bf16x8;

__device__ inline unsigned short f2bf(float f) {
    unsigned u = __float_as_uint(f);
    u += 0x7fffu + ((u >> 16) & 1u);   // round-to-nearest-even
    return (unsigned short)(u >> 16);
}
__device__ inline float bf2f(unsigned short h) {
    unsigned u = ((unsigned)h) << 16;
    return __uint_as_float(u);
}

// ---------------- row scale: scale[r] = 1/(rowsum + 1e-4) ----------------
__global__ void rowscale_kernel(const float* __restrict__ in, float* __restrict__ scale) {
    __shared__ float red[256];
    int r = blockIdx.x, t = threadIdx.x;
    float2 v = ((const float2*)(in + (size_t)r * DD))[t];
    red[t] = v.x + v.y;
    __syncthreads();
    for (int st = 128; st > 0; st >>= 1) {
        if (t < st) red[t] += red[t + st];
        __syncthreads();
    }
    if (t == 0) scale[r] = 1.0f / (red[0] + 1e-4f);
}

// ---------------- final L2 normalize + cast to bf16 ----------------
__global__ void l2norm_kernel(const float* __restrict__ in, unsigned short* __restrict__ emb) {
    __shared__ float red[256];
    int r = blockIdx.x, t = threadIdx.x;
    float2 v = ((const float2*)(in + (size_t)r * DD))[t];
    red[t] = v.x * v.x + v.y * v.y;
    __syncthreads();
    for (int st = 128; st > 0; st >>= 1) {
        if (t < st) red[t] += red[t + st];
        __syncthreads();
    }
    float norm = sqrtf(red[0]);
    float scale = 1.0f / fmaxf(norm, 1e-12f);
    ushort2 o;
    o.x = f2bf(v.x * scale);
    o.y = f2bf(v.y * scale);
    ((ushort2*)(emb + (size_t)r * DD))[t] = o;
}

// ================= CSR build (once; edge_index constant across layers) ======
__global__ void hist_kernel(const int* __restrict__ ei, int* __restrict__ cnt) {
    int e = blockIdx.x * 256 + threadIdx.x;
    atomicAdd(&cnt[ei[e]], 1);
}

__global__ void scan_kernel(int* __restrict__ cnt, int* __restrict__ row_ptr) {
    __shared__ int part[256];
    int t = threadIdx.x;
    int base = t * 32;
    int local[32];
    int s = 0;
#pragma unroll
    for (int i = 0; i < 32; ++i) { local[i] = s; s += cnt[base + i]; }
    part[t] = s;
    __syncthreads();
    for (int st = 1; st < 256; st <<= 1) {
        int add = (t >= st) ? part[t - st] : 0;
        __syncthreads();
        part[t] += add;
        __syncthreads();
    }
    int offset = part[t] - s;
#pragma unroll
    for (int i = 0; i < 32; ++i) {
        row_ptr[base + i] = offset + local[i];
        cnt[base + i] = offset + local[i];
    }
    if (t == 255) row_ptr[NN] = part[255];
}

__global__ void scatter_kernel(const int* __restrict__ ei, const float* __restrict__ ew,
                               int* __restrict__ cursor, int* __restrict__ s_src,
                               float* __restrict__ s_w) {
    int e = blockIdx.x * 256 + threadIdx.x;
    int dst = ei[e];
    int pos = atomicAdd(&cursor[dst], 1);
    s_src[pos] = ei[EE + e];
    s_w[pos]   = ew[e];
}

// ---------------- split W into bf16 hi/lo (once; W shared by both layers) ----------------
__global__ void splitW_kernel(const float* __restrict__ W, unsigned short* __restrict__ Whi,
                              unsigned short* __restrict__ Wlo) {
    int i = blockIdx.x * 256 + threadIdx.x;   // float2 index
    float2 w = ((const float2*)W)[i];
    ushort2 h, l;
    h.x = f2bf(w.x); l.x = f2bf(w.x - bf2f(h.x));
    h.y = f2bf(w.y); l.y = f2bf(w.y - bf2f(h.y));
    ((ushort2*)Whi)[i] = h;
    ((ushort2*)Wlo)[i] = l;
}

// ---------------- per-edge combined weight: sw2[e] = w[e] * scale[src[e]] ----------------
// Removes the s_src -> scale pointer-chase from the gather inner loop.
__global__ void edgew_kernel(const int* __restrict__ s_src, const float* __restrict__ s_w,
                             const float* __restrict__ scale, float* __restrict__ sw2) {
    int e = blockIdx.x * 256 + threadIdx.x;
    sw2[e] = s_w[e] * scale[s_src[e]];
}

// ---------------- SpMM gather: ONE WAVE PER DEST ROW ----------------
// Lane l covers cols 4l..4l+3 and 256+4l..256+4l+3 (two fully-coalesced
// dwordx4 per x-row). 2-edge unroll -> 4 independent 1KB row loads in
// flight per wave; independent acc chains; no barriers, no LDS.
// Edge metadata via readfirstlane-pinned scalar loads (constant cache).
__global__ __launch_bounds__(256) void gather_spmm_bf16(const int* __restrict__ row_ptr,
                                                        const int* __restrict__ s_src,
                                                        const float* __restrict__ sw2,
                                                        const float* __restrict__ x,
                                                        unsigned short* __restrict__ Ahi,
                                                        unsigned short* __restrict__ Alo) {
    int l = threadIdx.x & 63;
    int r = __builtin_amdgcn_readfirstlane(blockIdx.x * 4 + (threadIdx.x >> 6));
    int beg = row_ptr[r], end = row_ptr[r + 1];
    const f32x4* xv = (const f32x4*)x;   // row stride = 128 f32x4
    f32x4 a0 = {0.0f, 0.0f, 0.0f, 0.0f}, a1 = a0, b0 = a0, b1 = a0;
    int e = beg;
    for (; e + 2 <= end; e += 2) {
        int s0 = s_src[e], s1 = s_src[e + 1];
        float w0 = sw2[e], w1 = sw2[e + 1];
        const f32x4* r0 = xv + (size_t)s0 * 128;
        const f32x4* r1 = xv + (size_t)s1 * 128;
        f32x4 v00 = r0[l], v01 = r0[64 + l];
        f32x4 v10 = r1[l], v11 = r1[64 + l];
        a0 += w0 * v00; a1 += w0 * v01;
        b0 += w1 * v10; b1 += w1 * v11;
    }
    if (e < end) {
        int s0 = s_src[e];
        float w0 = sw2[e];
        const f32x4* r0 = xv + (size_t)s0 * 128;
        a0 += w0 * r0[l];
        a1 += w0 * r0[64 + l];
    }
    a0 += b0; a1 += b1;
    ushort4 h0, l0, h1, l1;
    h0.x = f2bf(a0.x); l0.x = f2bf(a0.x - bf2f(h0.x));
    h0.y = f2bf(a0.y); l0.y = f2bf(a0.y - bf2f(h0.y));
    h0.z = f2bf(a0.z); l0.z = f2bf(a0.z - bf2f(h0.z));
    h0.w = f2bf(a0.w); l0.w = f2bf(a0.w - bf2f(h0.w));
    h1.x = f2bf(a1.x); l1.x = f2bf(a1.x - bf2f(h1.x));
    h1.y = f2bf(a1.y); l1.y = f2bf(a1.y - bf2f(h1.y));
    h1.z = f2bf(a1.z); l1.z = f2bf(a1.z - bf2f(h1.z));
    h1.w = f2bf(a1.w); l1.w = f2bf(a1.w - bf2f(h1.w));
    size_t ro = (size_t)r * DD;
    *(ushort4*)&Ahi[ro + l * 4]       = h0;
    *(ushort4*)&Alo[ro + l * 4]       = l0;
    *(ushort4*)&Ahi[ro + 256 + l * 4] = h1;
    *(ushort4*)&Alo[ro + 256 + l * 4] = l1;
}

// ---------------- async global->LDS helper ----------------
__device__ inline void gl_lds16(const void* g, void* l) {
    __builtin_amdgcn_global_load_lds((const __attribute__((address_space(1))) void*)g,
                                     (__attribute__((address_space(3))) void*)l, 16, 0, 0);
}

// ---------------- layer GEMM: C = elu(A @ W^T + b), bf16-split MFMA ----------------
// A = Ahi+Alo [M=NN][K=DD], W = Whi+Wlo [N=DD][K=DD] (both row-major NT),
// acc += AhiWhi + AhiWlo + AloWhi  (AloWlo term ~2^-18 relative, dropped).
__global__ __launch_bounds__(256, 2) void gemm_split_mfma(const unsigned short* __restrict__ Ahi,
                                                          const unsigned short* __restrict__ Alo,
                                                          const unsigned short* __restrict__ Whi,
                                                          const unsigned short* __restrict__ Wlo,
                                                          const float* __restrict__ bias,
                                                          float* __restrict__ C) {
    __shared__ unsigned short lsAh[128 * 32], lsAl[128 * 32];
    __shared__ unsigned short lsBh[128 * 32], lsBl[128 * 32];
    const int K = DD;
    int tid = threadIdx.x;
    int wave = tid >> 6, lane = tid & 63;
    int quad = lane >> 4, l16 = lane & 15;
    // XCD-aware swizzle (grid 64x4 = 256 wgs, %8==0 -> simple form bijective)
    int lin = blockIdx.y * 64 + blockIdx.x;
    int sw  = (lin & 7) * 32 + (lin >> 3);
    int row0 = (sw & 63) * 128, col0 = (sw >> 6) * 128;
    int wm = (wave >> 1) * 64, wn = (wave & 1) * 64;

    f32x4 acc[4][4] = {};

    int ofs0 = tid * 16;
    for (int k0 = 0; k0 < K; k0 += 32) {
        __syncthreads();
#pragma unroll
        for (int rnd = 0; rnd < 2; ++rnd) {
            int ofs = rnd * 4096 + ofs0;
            int r = ofs >> 6;            // 64 B per 32-elem bf16 tile row
            int c = (ofs & 63) >> 1;
            size_t ga = (size_t)(row0 + r) * K + (k0 + c);
            size_t gb = (size_t)(col0 + r) * K + (k0 + c);
            int lofs = rnd * 4096 + wave * 1024;   // wave-uniform LDS base
            gl_lds16(Ahi + ga, (char*)lsAh + lofs);
            gl_lds16(Alo + ga, (char*)lsAl + lofs);
            gl_lds16(Whi + gb, (char*)lsBh + lofs);
            gl_lds16(Wlo + gb, (char*)lsBl + lofs);
        }
        __syncthreads();

        bf16x8 ah[4], al[4], bh[4], bl[4];
#pragma unroll
        for (int mt = 0; mt < 4; ++mt) {
            int o = (wm + mt * 16 + l16) * 32 + quad * 8;
            ah[mt] = *(const bf16x8*)&lsAh[o];
            al[mt] = *(const bf16x8*)&lsAl[o];
        }
#pragma unroll
        for (int nt = 0; nt < 4; ++nt) {
            int o = (wn + nt * 16 + l16) * 32 + quad * 8;
            bh[nt] = *(const bf16x8*)&lsBh[o];
            bl[nt] = *(const bf16x8*)&lsBl[o];
        }
#pragma unroll
        for (int mt = 0; mt < 4; ++mt)
#pragma unroll
            for (int nt = 0; nt < 4; ++nt) {
                acc[mt][nt] = __builtin_amdgcn_mfma_f32_16x16x32_bf16(ah[mt], bh[nt], acc[mt][nt], 0, 0, 0);
                acc[mt][nt] = __builtin_amdgcn_mfma_f32_16x16x32_bf16(ah[mt], bl[nt], acc[mt][nt], 0, 0, 0);
                acc[mt][nt] = __builtin_amdgcn_mfma_f32_16x16x32_bf16(al[mt], bh[nt], acc[mt][nt], 0, 0, 0);
            }
    }

    // C/D layout: col = lane&15, row = quad*4 + reg
#pragma unroll
    for (int mt = 0; mt < 4; ++mt)
#pragma unroll
        for (int nt = 0; nt < 4; ++nt)
#pragma unroll
            for (int i = 0; i < 4; ++i) {
                int r = row0 + wm + mt * 16 + quad * 4 + i;
                int c = col0 + wn + nt * 16 + l16;
                float v = acc[mt][nt][i] + bias[c];
                C[(size_t)r * DD + c] = v > 0.0f ? v : expm1f(v);
            }
}

// ---------------- similarity GEMM: out = relu(emb @ emb^T), bf16 MFMA ----------------
__global__ __launch_bounds__(256, 2) void simgemm_kernel(const unsigned short* __restrict__ A,
                                                         float* __restrict__ C) {
    __shared__ unsigned short lsA[128 * 32];
    __shared__ unsigned short lsB[128 * 32];
    const int K = DD;
    int tid = threadIdx.x;
    int wave = tid >> 6, lane = tid & 63;
    int quad = lane >> 4, l16 = lane & 15;
    // XCD-aware swizzle (grid 64x64 = 4096 wgs, %8==0 -> simple form bijective)
    int lin = blockIdx.y * 64 + blockIdx.x;
    int sw  = (lin & 7) * 512 + (lin >> 3);
    int row0 = (sw & 63) * 128, col0 = (sw >> 6) * 128;
    int wm = (wave >> 1) * 64, wn = (wave & 1) * 64;

    f32x4 acc[4][4] = {};

    int ofs0 = tid * 16;
    for (int k0 = 0; k0 < K; k0 += 32) {
        __syncthreads();
#pragma unroll
        for (int rnd = 0; rnd < 2; ++rnd) {
            int ofs = rnd * 4096 + ofs0;
            int r = ofs >> 6;
            int c = (ofs & 63) >> 1;
            const unsigned short* ga = A + (size_t)(row0 + r) * K + (k0 + c);
            const unsigned short* gb = A + (size_t)(col0 + r) * K + (k0 + c);
            char* la = (char*)lsA + rnd * 4096 + wave * 1024;
            char* lb = (char*)lsB + rnd * 4096 + wave * 1024;
            gl_lds16(ga, la);
            gl_lds16(gb, lb);
        }
        __syncthreads();

        bf16x8 afr[4], bfr[4];
#pragma unroll
        for (int mt = 0; mt < 4; ++mt)
            afr[mt] = *(const bf16x8*)&lsA[(wm + mt * 16 + l16) * 32 + quad * 8];
#pragma unroll
        for (int nt = 0; nt < 4; ++nt)
            bfr[nt] = *(const bf16x8*)&lsB[(wn + nt * 16 + l16) * 32 + quad * 8];
#pragma unroll
        for (int mt = 0; mt < 4; ++mt)
#pragma unroll
            for (int nt = 0; nt < 4; ++nt)
                acc[mt][nt] = __builtin_amdgcn_mfma_f32_16x16x32_bf16(afr[mt], bfr[nt],
                                                                      acc[mt][nt], 0, 0, 0);
    }

#pragma unroll
    for (int mt = 0; mt < 4; ++mt)
#pragma unroll
        for (int nt = 0; nt < 4; ++nt)
#pragma unroll
            for (int i = 0; i < 4; ++i) {
                int r = row0 + wm + mt * 16 + quad * 4 + i;
                int c = col0 + wn + nt * 16 + l16;
                C[(size_t)r * NN + c] = fmaxf(acc[mt][nt][i], 0.0f);
            }
}

extern "C" void kernel_launch(void* const* d_in, const int* in_sizes, int n_in,
                              void* d_out, int out_size, void* d_ws, size_t ws_size,
                              hipStream_t stream) {
    const float* x  = (const float*)d_in[0];
    const int*   ei = (const int*)d_in[1];
    const float* ew = (const float*)d_in[2];
    const float* W  = (const float*)d_in[3];
    const float* b  = (const float*)d_in[4];
    float* out = (float*)d_out;

    // workspace layout:
    // y [NN*DD] f32 | Ahi [NN*DD] bf16 | Alo [NN*DD] bf16 | Whi,Wlo [DD*DD] bf16
    // | scale [NN] f32 | row_ptr [NN+1] | cur_cnt [NN] | s_src [EE] | s_w [EE] | sw2 [EE]
    float* y = (float*)d_ws;
    unsigned short* Ahi = (unsigned short*)(y + (size_t)NN * DD);
    unsigned short* Alo = Ahi + (size_t)NN * DD;
    unsigned short* Whi = Alo + (size_t)NN * DD;
    unsigned short* Wlo = Whi + (size_t)DD * DD;
    float* scale  = (float*)(Wlo + (size_t)DD * DD);
    int* row_ptr  = (int*)(scale + NN);
    int* cur_cnt  = row_ptr + (NN + 1);
    int* s_src    = cur_cnt + NN;
    float* s_w    = (float*)(s_src + EE);
    float* sw2    = s_w + EE;
    unsigned short* emb = Ahi;   // Ahi dead after layer-2 gemm

    // ---- CSR build (edges identical across layers) ----
    hipMemsetAsync(cur_cnt, 0, NN * sizeof(int), stream);
    hist_kernel<<<EE / 256, 256, 0, stream>>>(ei, cur_cnt);
    scan_kernel<<<1, 256, 0, stream>>>(cur_cnt, row_ptr);
    scatter_kernel<<<EE / 256, 256, 0, stream>>>(ei, ew, cur_cnt, s_src, s_w);
    splitW_kernel<<<(DD * DD / 2) / 256, 256, 0, stream>>>(W, Whi, Wlo);

    const float* cur = x;
    for (int layer = 0; layer < 2; ++layer) {
        rowscale_kernel<<<NN, 256, 0, stream>>>(cur, scale);
        edgew_kernel<<<EE / 256, 256, 0, stream>>>(s_src, s_w, scale, sw2);
        gather_spmm_bf16<<<NN / 4, 256, 0, stream>>>(row_ptr, s_src, sw2, cur, Ahi, Alo);
        gemm_split_mfma<<<dim3(NN / 128, DD / 128), 256, 0, stream>>>(Ahi, Alo, Whi, Wlo, b, y);
        cur = y;
    }
    l2norm_kernel<<<NN, 256, 0, stream>>>(y, emb);
    simgemm_kernel<<<dim3(NN / 128, NN / 128), 256, 0, stream>>>(emb, out);
}

// Round 4
// 605.597 us; speedup vs baseline: 1.0423x; 1.0423x over previous
//
#include <hip/hip_runtime.h>

#define NN 8192
#define DD 512
#define EE 262144
#define PADF 528   // padded f32 row stride (2112 B = 33 lines, odd -> full L2 set coverage)
#define SLCF 128   // gather slice width (cols): 8192*512B = 4 MiB working set per XCD L2

typedef __attribute__((ext_vector_type(4))) float f32x4;
typedef __attribute__((ext_vector_type(8))) short bf16x8;

__device__ inline unsigned short f2bf(float f) {
    unsigned u = __float_as_uint(f);
    u += 0x7fffu + ((u >> 16) & 1u);   // round-to-nearest-even
    return (unsigned short)(u >> 16);
}
__device__ inline float bf2f(unsigned short h) {
    unsigned u = ((unsigned)h) << 16;
    return __uint_as_float(u);
}

// ---------------- row scale: scale[r] = 1/(rowsum + 1e-4) ----------------
__global__ void rowscale_kernel(const float* __restrict__ in, int ldi, float* __restrict__ scale) {
    __shared__ float red[256];
    int r = blockIdx.x, t = threadIdx.x;
    float2 v = ((const float2*)(in + (size_t)r * ldi))[t];
    red[t] = v.x + v.y;
    __syncthreads();
    for (int st = 128; st > 0; st >>= 1) {
        if (t < st) red[t] += red[t + st];
        __syncthreads();
    }
    if (t == 0) scale[r] = 1.0f / (red[0] + 1e-4f);
}

// ---------------- final L2 normalize + cast to bf16 (reads padded y) ----------------
__global__ void l2norm_kernel(const float* __restrict__ in, unsigned short* __restrict__ emb) {
    __shared__ float red[256];
    int r = blockIdx.x, t = threadIdx.x;
    float2 v = ((const float2*)(in + (size_t)r * PADF))[t];
    red[t] = v.x * v.x + v.y * v.y;
    __syncthreads();
    for (int st = 128; st > 0; st >>= 1) {
        if (t < st) red[t] += red[t + st];
        __syncthreads();
    }
    float norm = sqrtf(red[0]);
    float scale = 1.0f / fmaxf(norm, 1e-12f);
    ushort2 o;
    o.x = f2bf(v.x * scale);
    o.y = f2bf(v.y * scale);
    ((ushort2*)(emb + (size_t)r * DD))[t] = o;
}

// ================= CSR build (once; edge_index constant across layers) ======
__global__ void hist_kernel(const int* __restrict__ ei, int* __restrict__ cnt) {
    int e = blockIdx.x * 256 + threadIdx.x;
    atomicAdd(&cnt[ei[e]], 1);
}

__global__ void scan_kernel(int* __restrict__ cnt, int* __restrict__ row_ptr) {
    __shared__ int part[256];
    int t = threadIdx.x;
    int base = t * 32;
    int local[32];
    int s = 0;
#pragma unroll
    for (int i = 0; i < 32; ++i) { local[i] = s; s += cnt[base + i]; }
    part[t] = s;
    __syncthreads();
    for (int st = 1; st < 256; st <<= 1) {
        int add = (t >= st) ? part[t - st] : 0;
        __syncthreads();
        part[t] += add;
        __syncthreads();
    }
    int offset = part[t] - s;
#pragma unroll
    for (int i = 0; i < 32; ++i) {
        row_ptr[base + i] = offset + local[i];
        cnt[base + i] = offset + local[i];
    }
    if (t == 255) row_ptr[NN] = part[255];
}

__global__ void scatter_kernel(const int* __restrict__ ei, const float* __restrict__ ew,
                               int* __restrict__ cursor, int* __restrict__ s_src,
                               float* __restrict__ s_w) {
    int e = blockIdx.x * 256 + threadIdx.x;
    int dst = ei[e];
    int pos = atomicAdd(&cursor[dst], 1);
    s_src[pos] = ei[EE + e];
    s_w[pos]   = ew[e];
}

// ---------------- split W into bf16 hi/lo (once; W shared by both layers) ----------------
__global__ void splitW_kernel(const float* __restrict__ W, unsigned short* __restrict__ Whi,
                              unsigned short* __restrict__ Wlo) {
    int i = blockIdx.x * 256 + threadIdx.x;   // float2 index
    float2 w = ((const float2*)W)[i];
    ushort2 h, l;
    h.x = f2bf(w.x); l.x = f2bf(w.x - bf2f(h.x));
    h.y = f2bf(w.y); l.y = f2bf(w.y - bf2f(h.y));
    ((ushort2*)Whi)[i] = h;
    ((ushort2*)Wlo)[i] = l;
}

// ---------------- per-edge combined weight: sw2[e] = w[e] * scale[src[e]] ----------------
__global__ void edgew_kernel(const int* __restrict__ s_src, const float* __restrict__ s_w,
                             const float* __restrict__ scale, float* __restrict__ sw2) {
    int e = blockIdx.x * 256 + threadIdx.x;
    sw2[e] = s_w[e] * scale[s_src[e]];
}

// ---------------- pad-copy x [NN][DD] -> xp [NN][PADF] ----------------
__global__ void padcopy_kernel(const float* __restrict__ in, float* __restrict__ out) {
    int i = blockIdx.x * 256 + threadIdx.x;   // f32x4 index over NN*128
    int r = i >> 7, c = i & 127;
    *(f32x4*)(out + (size_t)r * PADF + c * 4) = *(const f32x4*)(in + (size_t)r * DD + c * 4);
}

// ---------------- SpMM gather, L2-blocked by column slice ----------------
// grid (NN/4, DD/SLCF); one wave per (dest row, slice). Slice working set =
// 8192 rows x 512 B = 4 MiB -> resident in each XCD's L2 (padded stride 2112 B
// spreads lines over all sets). Lane l covers cols c0+2l, c0+2l+1 (8 B/lane;
// one fully-coalesced 512 B wave-load per edge). 4-edge unroll, 4 independent
// acc chains; wave-uniform scalar metadata; non-temporal output stores so the
// bf16 slices don't evict the x-slice.
__global__ __launch_bounds__(256) void gather_spmm_bf16(const int* __restrict__ row_ptr,
                                                        const int* __restrict__ s_src,
                                                        const float* __restrict__ sw2,
                                                        const float* __restrict__ xp,
                                                        unsigned short* __restrict__ Ahi,
                                                        unsigned short* __restrict__ Alo) {
    int l = threadIdx.x & 63;
    int r = __builtin_amdgcn_readfirstlane(blockIdx.x * 4 + (threadIdx.x >> 6));
    int c0 = blockIdx.y * SLCF;
    int beg = row_ptr[r], end = row_ptr[r + 1];
    float2 a0 = {0.0f, 0.0f}, a1 = a0, a2 = a0, a3 = a0;
    int e = beg;
    for (; e + 4 <= end; e += 4) {
        int s0 = s_src[e], s1 = s_src[e + 1], s2 = s_src[e + 2], s3 = s_src[e + 3];
        float w0 = sw2[e], w1 = sw2[e + 1], w2 = sw2[e + 2], w3 = sw2[e + 3];
        float2 v0 = ((const float2*)(xp + (size_t)s0 * PADF + c0))[l];
        float2 v1 = ((const float2*)(xp + (size_t)s1 * PADF + c0))[l];
        float2 v2 = ((const float2*)(xp + (size_t)s2 * PADF + c0))[l];
        float2 v3 = ((const float2*)(xp + (size_t)s3 * PADF + c0))[l];
        a0.x += w0 * v0.x; a0.y += w0 * v0.y;
        a1.x += w1 * v1.x; a1.y += w1 * v1.y;
        a2.x += w2 * v2.x; a2.y += w2 * v2.y;
        a3.x += w3 * v3.x; a3.y += w3 * v3.y;
    }
    for (; e < end; ++e) {
        int s0 = s_src[e];
        float w0 = sw2[e];
        float2 v0 = ((const float2*)(xp + (size_t)s0 * PADF + c0))[l];
        a0.x += w0 * v0.x; a0.y += w0 * v0.y;
    }
    float ox = (a0.x + a2.x) + (a1.x + a3.x);
    float oy = (a0.y + a2.y) + (a1.y + a3.y);
    unsigned short hx = f2bf(ox), lx = f2bf(ox - bf2f(hx));
    unsigned short hy = f2bf(oy), ly = f2bf(oy - bf2f(hy));
    unsigned hh = (unsigned)hx | ((unsigned)hy << 16);
    unsigned ll = (unsigned)lx | ((unsigned)ly << 16);
    size_t o = (size_t)r * DD + c0 + 2 * l;
    __builtin_nontemporal_store(hh, (unsigned*)&Ahi[o]);
    __builtin_nontemporal_store(ll, (unsigned*)&Alo[o]);
}

// ---------------- async global->LDS helper ----------------
__device__ inline void gl_lds16(const void* g, void* l) {
    __builtin_amdgcn_global_load_lds((const __attribute__((address_space(1))) void*)g,
                                     (__attribute__((address_space(3))) void*)l, 16, 0, 0);
}

// ---------------- layer GEMM: C = elu(A @ W^T + b), bf16-split MFMA ----------------
// A = Ahi+Alo [M=NN][K=DD] dense, W = Whi+Wlo [N=DD][K=DD] (row-major NT),
// acc += AhiWhi + AhiWlo + AloWhi; C written with padded stride PADF.
__global__ __launch_bounds__(256, 2) void gemm_split_mfma(const unsigned short* __restrict__ Ahi,
                                                          const unsigned short* __restrict__ Alo,
                                                          const unsigned short* __restrict__ Whi,
                                                          const unsigned short* __restrict__ Wlo,
                                                          const float* __restrict__ bias,
                                                          float* __restrict__ C) {
    __shared__ unsigned short lsAh[128 * 32], lsAl[128 * 32];
    __shared__ unsigned short lsBh[128 * 32], lsBl[128 * 32];
    const int K = DD;
    int tid = threadIdx.x;
    int wave = tid >> 6, lane = tid & 63;
    int quad = lane >> 4, l16 = lane & 15;
    // XCD-aware swizzle (grid 64x4 = 256 wgs, %8==0 -> simple form bijective)
    int lin = blockIdx.y * 64 + blockIdx.x;
    int sw  = (lin & 7) * 32 + (lin >> 3);
    int row0 = (sw & 63) * 128, col0 = (sw >> 6) * 128;
    int wm = (wave >> 1) * 64, wn = (wave & 1) * 64;

    f32x4 acc[4][4] = {};

    int ofs0 = tid * 16;
    for (int k0 = 0; k0 < K; k0 += 32) {
        __syncthreads();
#pragma unroll
        for (int rnd = 0; rnd < 2; ++rnd) {
            int ofs = rnd * 4096 + ofs0;
            int r = ofs >> 6;            // 64 B per 32-elem bf16 tile row
            int c = (ofs & 63) >> 1;
            size_t ga = (size_t)(row0 + r) * K + (k0 + c);
            size_t gb = (size_t)(col0 + r) * K + (k0 + c);
            int lofs = rnd * 4096 + wave * 1024;   // wave-uniform LDS base
            gl_lds16(Ahi + ga, (char*)lsAh + lofs);
            gl_lds16(Alo + ga, (char*)lsAl + lofs);
            gl_lds16(Whi + gb, (char*)lsBh + lofs);
            gl_lds16(Wlo + gb, (char*)lsBl + lofs);
        }
        __syncthreads();

        bf16x8 ah[4], al[4], bh[4], bl[4];
#pragma unroll
        for (int mt = 0; mt < 4; ++mt) {
            int o = (wm + mt * 16 + l16) * 32 + quad * 8;
            ah[mt] = *(const bf16x8*)&lsAh[o];
            al[mt] = *(const bf16x8*)&lsAl[o];
        }
#pragma unroll
        for (int nt = 0; nt < 4; ++nt) {
            int o = (wn + nt * 16 + l16) * 32 + quad * 8;
            bh[nt] = *(const bf16x8*)&lsBh[o];
            bl[nt] = *(const bf16x8*)&lsBl[o];
        }
#pragma unroll
        for (int mt = 0; mt < 4; ++mt)
#pragma unroll
            for (int nt = 0; nt < 4; ++nt) {
                acc[mt][nt] = __builtin_amdgcn_mfma_f32_16x16x32_bf16(ah[mt], bh[nt], acc[mt][nt], 0, 0, 0);
                acc[mt][nt] = __builtin_amdgcn_mfma_f32_16x16x32_bf16(ah[mt], bl[nt], acc[mt][nt], 0, 0, 0);
                acc[mt][nt] = __builtin_amdgcn_mfma_f32_16x16x32_bf16(al[mt], bh[nt], acc[mt][nt], 0, 0, 0);
            }
    }

    // C/D layout: col = lane&15, row = quad*4 + reg
#pragma unroll
    for (int mt = 0; mt < 4; ++mt)
#pragma unroll
        for (int nt = 0; nt < 4; ++nt)
#pragma unroll
            for (int i = 0; i < 4; ++i) {
                int r = row0 + wm + mt * 16 + quad * 4 + i;
                int c = col0 + wn + nt * 16 + l16;
                float v = acc[mt][nt][i] + bias[c];
                C[(size_t)r * PADF + c] = v > 0.0f ? v : expm1f(v);
            }
}

// ---------------- similarity GEMM: out = relu(emb @ emb^T), bf16 MFMA ----------------
__global__ __launch_bounds__(256, 2) void simgemm_kernel(const unsigned short* __restrict__ A,
                                                         float* __restrict__ C) {
    __shared__ unsigned short lsA[128 * 32];
    __shared__ unsigned short lsB[128 * 32];
    const int K = DD;
    int tid = threadIdx.x;
    int wave = tid >> 6, lane = tid & 63;
    int quad = lane >> 4, l16 = lane & 15;
    // XCD-aware swizzle (grid 64x64 = 4096 wgs, %8==0 -> simple form bijective)
    int lin = blockIdx.y * 64 + blockIdx.x;
    int sw  = (lin & 7) * 512 + (lin >> 3);
    int row0 = (sw & 63) * 128, col0 = (sw >> 6) * 128;
    int wm = (wave >> 1) * 64, wn = (wave & 1) * 64;

    f32x4 acc[4][4] = {};

    int ofs0 = tid * 16;
    for (int k0 = 0; k0 < K; k0 += 32) {
        __syncthreads();
#pragma unroll
        for (int rnd = 0; rnd < 2; ++rnd) {
            int ofs = rnd * 4096 + ofs0;
            int r = ofs >> 6;
            int c = (ofs & 63) >> 1;
            const unsigned short* ga = A + (size_t)(row0 + r) * K + (k0 + c);
            const unsigned short* gb = A + (size_t)(col0 + r) * K + (k0 + c);
            char* la = (char*)lsA + rnd * 4096 + wave * 1024;
            char* lb = (char*)lsB + rnd * 4096 + wave * 1024;
            gl_lds16(ga, la);
            gl_lds16(gb, lb);
        }
        __syncthreads();

        bf16x8 afr[4], bfr[4];
#pragma unroll
        for (int mt = 0; mt < 4; ++mt)
            afr[mt] = *(const bf16x8*)&lsA[(wm + mt * 16 + l16) * 32 + quad * 8];
#pragma unroll
        for (int nt = 0; nt < 4; ++nt)
            bfr[nt] = *(const bf16x8*)&lsB[(wn + nt * 16 + l16) * 32 + quad * 8];
#pragma unroll
        for (int mt = 0; mt < 4; ++mt)
#pragma unroll
            for (int nt = 0; nt < 4; ++nt)
                acc[mt][nt] = __builtin_amdgcn_mfma_f32_16x16x32_bf16(afr[mt], bfr[nt],
                                                                      acc[mt][nt], 0, 0, 0);
    }

#pragma unroll
    for (int mt = 0; mt < 4; ++mt)
#pragma unroll
        for (int nt = 0; nt < 4; ++nt)
#pragma unroll
            for (int i = 0; i < 4; ++i) {
                int r = row0 + wm + mt * 16 + quad * 4 + i;
                int c = col0 + wn + nt * 16 + l16;
                C[(size_t)r * NN + c] = fmaxf(acc[mt][nt][i], 0.0f);
            }
}

extern "C" void kernel_launch(void* const* d_in, const int* in_sizes, int n_in,
                              void* d_out, int out_size, void* d_ws, size_t ws_size,
                              hipStream_t stream) {
    const float* x  = (const float*)d_in[0];
    const int*   ei = (const int*)d_in[1];
    const float* ew = (const float*)d_in[2];
    const float* W  = (const float*)d_in[3];
    const float* b  = (const float*)d_in[4];
    float* out = (float*)d_out;

    // workspace layout:
    // y [NN*PADF] f32 | xp [NN*PADF] f32 | Ahi [NN*DD] bf16 | Alo [NN*DD] bf16
    // | Whi,Wlo [DD*DD] bf16 | scale [NN] f32 | row_ptr [NN+1] | cur_cnt [NN]
    // | s_src [EE] | s_w [EE] | sw2 [EE]
    float* y  = (float*)d_ws;
    float* xp = y + (size_t)NN * PADF;
    unsigned short* Ahi = (unsigned short*)(xp + (size_t)NN * PADF);
    unsigned short* Alo = Ahi + (size_t)NN * DD;
    unsigned short* Whi = Alo + (size_t)NN * DD;
    unsigned short* Wlo = Whi + (size_t)DD * DD;
    float* scale  = (float*)(Wlo + (size_t)DD * DD);
    int* row_ptr  = (int*)(scale + NN);
    int* cur_cnt  = row_ptr + (NN + 1);
    int* s_src    = cur_cnt + NN;
    float* s_w    = (float*)(s_src + EE);
    float* sw2    = s_w + EE;
    unsigned short* emb = Ahi;   // Ahi dead after layer-2 gemm

    // ---- CSR build (edges identical across layers) ----
    hipMemsetAsync(cur_cnt, 0, NN * sizeof(int), stream);
    hist_kernel<<<EE / 256, 256, 0, stream>>>(ei, cur_cnt);
    scan_kernel<<<1, 256, 0, stream>>>(cur_cnt, row_ptr);
    scatter_kernel<<<EE / 256, 256, 0, stream>>>(ei, ew, cur_cnt, s_src, s_w);
    splitW_kernel<<<(DD * DD / 2) / 256, 256, 0, stream>>>(W, Whi, Wlo);
    padcopy_kernel<<<NN * (DD / 4) / 256, 256, 0, stream>>>(x, xp);

    const float* cur = x;   // rowscale input (dense for layer 1)
    int ldcur = DD;
    const float* curp = xp; // gather input (padded)
    for (int layer = 0; layer < 2; ++layer) {
        rowscale_kernel<<<NN, 256, 0, stream>>>(cur, ldcur, scale);
        edgew_kernel<<<EE / 256, 256, 0, stream>>>(s_src, s_w, scale, sw2);
        gather_spmm_bf16<<<dim3(NN / 4, DD / SLCF), 256, 0, stream>>>(row_ptr, s_src, sw2, curp, Ahi, Alo);
        gemm_split_mfma<<<dim3(NN / 128, DD / 128), 256, 0, stream>>>(Ahi, Alo, Whi, Wlo, b, y);
        cur = y; ldcur = PADF; curp = y;
    }
    l2norm_kernel<<<NN, 256, 0, stream>>>(y, emb);
    simgemm_kernel<<<dim3(NN / 128, NN / 128), 256, 0, stream>>>(emb, out);
}

// Round 5
// 604.642 us; speedup vs baseline: 1.0440x; 1.0016x over previous
//
#include <hip/hip_runtime.h>

#define NN 8192
#define DD 512
#define EE 262144
#define PADF 528   // padded f32 row stride (2112 B = 33 lines, odd -> full L2 set coverage)
#define SLCF 64    // gather slice width (cols): 8192*256B = 2 MiB per XCD L2 (+2 MiB headroom)

typedef __attribute__((ext_vector_type(4))) float f32x4;
typedef __attribute__((ext_vector_type(8))) short bf16x8;

__device__ inline unsigned short f2bf(float f) {
    unsigned u = __float_as_uint(f);
    u += 0x7fffu + ((u >> 16) & 1u);   // round-to-nearest-even
    return (unsigned short)(u >> 16);
}
__device__ inline float bf2f(unsigned short h) {
    unsigned u = ((unsigned)h) << 16;
    return __uint_as_float(u);
}

// ---------------- row scale: scale[r] = 1/(rowsum + 1e-4) ----------------
__global__ void rowscale_kernel(const float* __restrict__ in, int ldi, float* __restrict__ scale) {
    __shared__ float red[256];
    int r = blockIdx.x, t = threadIdx.x;
    float2 v = ((const float2*)(in + (size_t)r * ldi))[t];
    red[t] = v.x + v.y;
    __syncthreads();
    for (int st = 128; st > 0; st >>= 1) {
        if (t < st) red[t] += red[t + st];
        __syncthreads();
    }
    if (t == 0) scale[r] = 1.0f / (red[0] + 1e-4f);
}

// ---------------- final L2 normalize + cast to bf16 (reads padded y) ----------------
__global__ void l2norm_kernel(const float* __restrict__ in, unsigned short* __restrict__ emb) {
    __shared__ float red[256];
    int r = blockIdx.x, t = threadIdx.x;
    float2 v = ((const float2*)(in + (size_t)r * PADF))[t];
    red[t] = v.x * v.x + v.y * v.y;
    __syncthreads();
    for (int st = 128; st > 0; st >>= 1) {
        if (t < st) red[t] += red[t + st];
        __syncthreads();
    }
    float norm = sqrtf(red[0]);
    float scale = 1.0f / fmaxf(norm, 1e-12f);
    ushort2 o;
    o.x = f2bf(v.x * scale);
    o.y = f2bf(v.y * scale);
    ((ushort2*)(emb + (size_t)r * DD))[t] = o;
}

// ================= CSR build (once; edge_index constant across layers) ======
__global__ void hist_kernel(const int* __restrict__ ei, int* __restrict__ cnt) {
    int e = blockIdx.x * 256 + threadIdx.x;
    atomicAdd(&cnt[ei[e]], 1);
}

__global__ void scan_kernel(int* __restrict__ cnt, int* __restrict__ row_ptr) {
    __shared__ int part[256];
    int t = threadIdx.x;
    int base = t * 32;
    int local[32];
    int s = 0;
#pragma unroll
    for (int i = 0; i < 32; ++i) { local[i] = s; s += cnt[base + i]; }
    part[t] = s;
    __syncthreads();
    for (int st = 1; st < 256; st <<= 1) {
        int add = (t >= st) ? part[t - st] : 0;
        __syncthreads();
        part[t] += add;
        __syncthreads();
    }
    int offset = part[t] - s;
#pragma unroll
    for (int i = 0; i < 32; ++i) {
        row_ptr[base + i] = offset + local[i];
        cnt[base + i] = offset + local[i];
    }
    if (t == 255) row_ptr[NN] = part[255];
}

__global__ void scatter_kernel(const int* __restrict__ ei, const float* __restrict__ ew,
                               int* __restrict__ cursor, int* __restrict__ s_src,
                               float* __restrict__ s_w) {
    int e = blockIdx.x * 256 + threadIdx.x;
    int dst = ei[e];
    int pos = atomicAdd(&cursor[dst], 1);
    s_src[pos] = ei[EE + e];
    s_w[pos]   = ew[e];
}

// ---------------- split W into bf16 hi/lo (once; W shared by both layers) ----------------
__global__ void splitW_kernel(const float* __restrict__ W, unsigned short* __restrict__ Whi,
                              unsigned short* __restrict__ Wlo) {
    int i = blockIdx.x * 256 + threadIdx.x;   // float2 index
    float2 w = ((const float2*)W)[i];
    ushort2 h, l;
    h.x = f2bf(w.x); l.x = f2bf(w.x - bf2f(h.x));
    h.y = f2bf(w.y); l.y = f2bf(w.y - bf2f(h.y));
    ((ushort2*)Whi)[i] = h;
    ((ushort2*)Wlo)[i] = l;
}

// ---------------- per-edge combined weight: sw2[e] = w[e] * scale[src[e]] ----------------
__global__ void edgew_kernel(const int* __restrict__ s_src, const float* __restrict__ s_w,
                             const float* __restrict__ scale, float* __restrict__ sw2) {
    int e = blockIdx.x * 256 + threadIdx.x;
    sw2[e] = s_w[e] * scale[s_src[e]];
}

// ---------------- pad-copy x [NN][DD] -> xp [NN][PADF] ----------------
__global__ void padcopy_kernel(const float* __restrict__ in, float* __restrict__ out) {
    int i = blockIdx.x * 256 + threadIdx.x;   // f32x4 index over NN*128
    int r = i >> 7, c = i & 127;
    *(f32x4*)(out + (size_t)r * PADF + c * 4) = *(const f32x4*)(in + (size_t)r * DD + c * 4);
}

// ---------------- SpMM gather, L2-blocked by 64-col slice ----------------
// grid (NN/4, DD/SLCF); one wave per (dest row, slice). Slice working set =
// 8192 x 256 B = 2 MiB -> resident in each XCD's 4 MiB L2 with headroom for
// the output store stream + metadata. Lane l covers col c0+l (4 B/lane; one
// coalesced 256 B wave-load per edge). 4-edge unroll, 4 independent acc
// chains; wave-uniform scalar metadata; non-temporal output stores.
__global__ __launch_bounds__(256) void gather_spmm_bf16(const int* __restrict__ row_ptr,
                                                        const int* __restrict__ s_src,
                                                        const float* __restrict__ sw2,
                                                        const float* __restrict__ xp,
                                                        unsigned short* __restrict__ Ahi,
                                                        unsigned short* __restrict__ Alo) {
    int l = threadIdx.x & 63;
    int r = __builtin_amdgcn_readfirstlane(blockIdx.x * 4 + (threadIdx.x >> 6));
    int c0 = blockIdx.y * SLCF;
    int beg = row_ptr[r], end = row_ptr[r + 1];
    const float* xs = xp + c0 + l;
    float a0 = 0.0f, a1 = 0.0f, a2 = 0.0f, a3 = 0.0f;
    int e = beg;
    for (; e + 4 <= end; e += 4) {
        int s0 = s_src[e], s1 = s_src[e + 1], s2 = s_src[e + 2], s3 = s_src[e + 3];
        float w0 = sw2[e], w1 = sw2[e + 1], w2 = sw2[e + 2], w3 = sw2[e + 3];
        float v0 = xs[(size_t)s0 * PADF];
        float v1 = xs[(size_t)s1 * PADF];
        float v2 = xs[(size_t)s2 * PADF];
        float v3 = xs[(size_t)s3 * PADF];
        a0 += w0 * v0;
        a1 += w1 * v1;
        a2 += w2 * v2;
        a3 += w3 * v3;
    }
    for (; e < end; ++e) {
        a0 += sw2[e] * xs[(size_t)s_src[e] * PADF];
    }
    float o = (a0 + a2) + (a1 + a3);
    unsigned short h = f2bf(o);
    unsigned short lo = f2bf(o - bf2f(h));
    size_t oofs = (size_t)r * DD + c0 + l;
    __builtin_nontemporal_store(h,  &Ahi[oofs]);
    __builtin_nontemporal_store(lo, &Alo[oofs]);
}

// ---------------- async global->LDS helper ----------------
__device__ inline void gl_lds16(const void* g, void* l) {
    __builtin_amdgcn_global_load_lds((const __attribute__((address_space(1))) void*)g,
                                     (__attribute__((address_space(3))) void*)l, 16, 0, 0);
}

// ---------------- layer GEMM: C = elu(A @ W^T + b), bf16-split MFMA ----------------
// BM=64, BN=128, BK=64 (two [rows][32] sub-tiles per stage -> fragment reads
// bank-identical to the proven BK=32 code; barriers halved). Grid (128,4) =
// 512 wgs = 2+ blocks/CU so barrier drains overlap across blocks.
// acc += AhiWhi + AhiWlo + AloWhi  (AloWlo ~2^-18 relative, dropped).
__global__ __launch_bounds__(256, 2) void gemm_split_mfma(const unsigned short* __restrict__ Ahi,
                                                          const unsigned short* __restrict__ Alo,
                                                          const unsigned short* __restrict__ Whi,
                                                          const unsigned short* __restrict__ Wlo,
                                                          const float* __restrict__ bias,
                                                          float* __restrict__ C) {
    __shared__ unsigned short lsAh[2][64 * 32], lsAl[2][64 * 32];     // 4 KB per sub
    __shared__ unsigned short lsBh[2][128 * 32], lsBl[2][128 * 32];   // 8 KB per sub
    const int K = DD;
    int tid = threadIdx.x;
    int wave = tid >> 6, lane = tid & 63;
    int quad = lane >> 4, l16 = lane & 15;
    // XCD-aware swizzle (512 wgs, %8==0 -> simple form bijective)
    int lin = blockIdx.y * 128 + blockIdx.x;
    int sw  = (lin & 7) * 64 + (lin >> 3);
    int row0 = (sw & 127) * 64, col0 = (sw >> 7) * 128;
    int wm = (wave >> 1) * 32, wn = (wave & 1) * 64;

    f32x4 acc[2][4] = {};

    int ofs0 = tid * 16;
    for (int k0 = 0; k0 < K; k0 += 64) {
        __syncthreads();
#pragma unroll
        for (int sub = 0; sub < 2; ++sub) {
            int ks = k0 + sub * 32;
            {   // A sub-tile: 64 rows x 32 cols = 4 KB per array -> 1 instr each
                int r = ofs0 >> 6;
                int c = (ofs0 & 63) >> 1;
                size_t ga = (size_t)(row0 + r) * K + (ks + c);
                int lofs = wave * 1024;
                gl_lds16(Ahi + ga, (char*)lsAh[sub] + lofs);
                gl_lds16(Alo + ga, (char*)lsAl[sub] + lofs);
            }
#pragma unroll
            for (int rnd = 0; rnd < 2; ++rnd) {  // B sub-tile: 128x32 = 8 KB -> 2 instr each
                int ofs = rnd * 4096 + ofs0;
                int r = ofs >> 6;
                int c = (ofs & 63) >> 1;
                size_t gb = (size_t)(col0 + r) * K + (ks + c);
                int lofs = rnd * 4096 + wave * 1024;
                gl_lds16(Whi + gb, (char*)lsBh[sub] + lofs);
                gl_lds16(Wlo + gb, (char*)lsBl[sub] + lofs);
            }
        }
        __syncthreads();

#pragma unroll
        for (int sub = 0; sub < 2; ++sub) {
            bf16x8 ah[2], al[2], bh[4], bl[4];
#pragma unroll
            for (int mt = 0; mt < 2; ++mt) {
                int o = (wm + mt * 16 + l16) * 32 + quad * 8;
                ah[mt] = *(const bf16x8*)&lsAh[sub][o];
                al[mt] = *(const bf16x8*)&lsAl[sub][o];
            }
#pragma unroll
            for (int nt = 0; nt < 4; ++nt) {
                int o = (wn + nt * 16 + l16) * 32 + quad * 8;
                bh[nt] = *(const bf16x8*)&lsBh[sub][o];
                bl[nt] = *(const bf16x8*)&lsBl[sub][o];
            }
#pragma unroll
            for (int mt = 0; mt < 2; ++mt)
#pragma unroll
                for (int nt = 0; nt < 4; ++nt) {
                    acc[mt][nt] = __builtin_amdgcn_mfma_f32_16x16x32_bf16(ah[mt], bh[nt], acc[mt][nt], 0, 0, 0);
                    acc[mt][nt] = __builtin_amdgcn_mfma_f32_16x16x32_bf16(ah[mt], bl[nt], acc[mt][nt], 0, 0, 0);
                    acc[mt][nt] = __builtin_amdgcn_mfma_f32_16x16x32_bf16(al[mt], bh[nt], acc[mt][nt], 0, 0, 0);
                }
        }
    }

    // C/D layout: col = lane&15, row = quad*4 + reg
#pragma unroll
    for (int mt = 0; mt < 2; ++mt)
#pragma unroll
        for (int nt = 0; nt < 4; ++nt)
#pragma unroll
            for (int i = 0; i < 4; ++i) {
                int r = row0 + wm + mt * 16 + quad * 4 + i;
                int c = col0 + wn + nt * 16 + l16;
                float v = acc[mt][nt][i] + bias[c];
                C[(size_t)r * PADF + c] = v > 0.0f ? v : expm1f(v);
            }
}

// ---------------- similarity GEMM: out = relu(emb @ emb^T), bf16 MFMA ----------------
// 128x128 tile, BK=64 as two [128][32] sub-tiles (fragment reads bank-identical
// to proven BK=32 code; barrier count halved: 8 stages over K=512).
__global__ __launch_bounds__(256, 2) void simgemm_kernel(const unsigned short* __restrict__ A,
                                                         float* __restrict__ C) {
    __shared__ unsigned short lsA[2][128 * 32];
    __shared__ unsigned short lsB[2][128 * 32];
    const int K = DD;
    int tid = threadIdx.x;
    int wave = tid >> 6, lane = tid & 63;
    int quad = lane >> 4, l16 = lane & 15;
    // XCD-aware swizzle (grid 64x64 = 4096 wgs, %8==0 -> simple form bijective)
    int lin = blockIdx.y * 64 + blockIdx.x;
    int sw  = (lin & 7) * 512 + (lin >> 3);
    int row0 = (sw & 63) * 128, col0 = (sw >> 6) * 128;
    int wm = (wave >> 1) * 64, wn = (wave & 1) * 64;

    f32x4 acc[4][4] = {};

    int ofs0 = tid * 16;
    for (int k0 = 0; k0 < K; k0 += 64) {
        __syncthreads();
#pragma unroll
        for (int sub = 0; sub < 2; ++sub) {
            int ks = k0 + sub * 32;
#pragma unroll
            for (int rnd = 0; rnd < 2; ++rnd) {
                int ofs = rnd * 4096 + ofs0;
                int r = ofs >> 6;
                int c = (ofs & 63) >> 1;
                const unsigned short* ga = A + (size_t)(row0 + r) * K + (ks + c);
                const unsigned short* gb = A + (size_t)(col0 + r) * K + (ks + c);
                int lofs = rnd * 4096 + wave * 1024;
                gl_lds16(ga, (char*)lsA[sub] + lofs);
                gl_lds16(gb, (char*)lsB[sub] + lofs);
            }
        }
        __syncthreads();

#pragma unroll
        for (int sub = 0; sub < 2; ++sub) {
            bf16x8 afr[4], bfr[4];
#pragma unroll
            for (int mt = 0; mt < 4; ++mt)
                afr[mt] = *(const bf16x8*)&lsA[sub][(wm + mt * 16 + l16) * 32 + quad * 8];
#pragma unroll
            for (int nt = 0; nt < 4; ++nt)
                bfr[nt] = *(const bf16x8*)&lsB[sub][(wn + nt * 16 + l16) * 32 + quad * 8];
#pragma unroll
            for (int mt = 0; mt < 4; ++mt)
#pragma unroll
                for (int nt = 0; nt < 4; ++nt)
                    acc[mt][nt] = __builtin_amdgcn_mfma_f32_16x16x32_bf16(afr[mt], bfr[nt],
                                                                          acc[mt][nt], 0, 0, 0);
        }
    }

#pragma unroll
    for (int mt = 0; mt < 4; ++mt)
#pragma unroll
        for (int nt = 0; nt < 4; ++nt)
#pragma unroll
            for (int i = 0; i < 4; ++i) {
                int r = row0 + wm + mt * 16 + quad * 4 + i;
                int c = col0 + wn + nt * 16 + l16;
                C[(size_t)r * NN + c] = fmaxf(acc[mt][nt][i], 0.0f);
            }
}

extern "C" void kernel_launch(void* const* d_in, const int* in_sizes, int n_in,
                              void* d_out, int out_size, void* d_ws, size_t ws_size,
                              hipStream_t stream) {
    const float* x  = (const float*)d_in[0];
    const int*   ei = (const int*)d_in[1];
    const float* ew = (const float*)d_in[2];
    const float* W  = (const float*)d_in[3];
    const float* b  = (const float*)d_in[4];
    float* out = (float*)d_out;

    // workspace layout:
    // y [NN*PADF] f32 | xp [NN*PADF] f32 | Ahi [NN*DD] bf16 | Alo [NN*DD] bf16
    // | Whi,Wlo [DD*DD] bf16 | scale [NN] f32 | row_ptr [NN+1] | cur_cnt [NN]
    // | s_src [EE] | s_w [EE] | sw2 [EE]
    float* y  = (float*)d_ws;
    float* xp = y + (size_t)NN * PADF;
    unsigned short* Ahi = (unsigned short*)(xp + (size_t)NN * PADF);
    unsigned short* Alo = Ahi + (size_t)NN * DD;
    unsigned short* Whi = Alo + (size_t)NN * DD;
    unsigned short* Wlo = Whi + (size_t)DD * DD;
    float* scale  = (float*)(Wlo + (size_t)DD * DD);
    int* row_ptr  = (int*)(scale + NN);
    int* cur_cnt  = row_ptr + (NN + 1);
    int* s_src    = cur_cnt + NN;
    float* s_w    = (float*)(s_src + EE);
    float* sw2    = s_w + EE;
    unsigned short* emb = Ahi;   // Ahi dead after layer-2 gemm

    // ---- CSR build (edges identical across layers) ----
    hipMemsetAsync(cur_cnt, 0, NN * sizeof(int), stream);
    hist_kernel<<<EE / 256, 256, 0, stream>>>(ei, cur_cnt);
    scan_kernel<<<1, 256, 0, stream>>>(cur_cnt, row_ptr);
    scatter_kernel<<<EE / 256, 256, 0, stream>>>(ei, ew, cur_cnt, s_src, s_w);
    splitW_kernel<<<(DD * DD / 2) / 256, 256, 0, stream>>>(W, Whi, Wlo);
    padcopy_kernel<<<NN * (DD / 4) / 256, 256, 0, stream>>>(x, xp);

    const float* cur = x;   // rowscale input (dense for layer 1)
    int ldcur = DD;
    const float* curp = xp; // gather input (padded)
    for (int layer = 0; layer < 2; ++layer) {
        rowscale_kernel<<<NN, 256, 0, stream>>>(cur, ldcur, scale);
        edgew_kernel<<<EE / 256, 256, 0, stream>>>(s_src, s_w, scale, sw2);
        gather_spmm_bf16<<<dim3(NN / 4, DD / SLCF), 256, 0, stream>>>(row_ptr, s_src, sw2, curp, Ahi, Alo);
        gemm_split_mfma<<<dim3(NN / 64, DD / 128), 256, 0, stream>>>(Ahi, Alo, Whi, Wlo, b, y);
        cur = y; ldcur = PADF; curp = y;
    }
    l2norm_kernel<<<NN, 256, 0, stream>>>(y, emb);
    simgemm_kernel<<<dim3(NN / 128, NN / 128), 256, 0, stream>>>(emb, out);
}